// Round 2
// baseline (238.151 us; speedup 1.0000x reference)
//
#include <hip/hip_runtime.h>
#include <math.h>

// Problem constants (fixed by setup_inputs)
#define B_TOTAL 131072
#define K_COMP  64
#define D_DIM   8
#define NC      36
#define CPK     48   // coeff floats per component: 28 S + 8 r + 8 mu + 1 const + 3 pad
#define KPT     16   // components per thread (4 threads per row)

// norm_const = -0.5 * D * log(2*pi)
#define NORM_CONST (-7.3515082656373815f)

// ---------------------------------------------------------------------------
// Precompute per-component coefficients into d_ws:
//   [0..27]  S_ij = L_ij / L_ii   (i=1..7, j<i, index i*(i-1)/2+j)
//   [28..35] r_i  = 1 / L_ii
//   [36..43] mu_k[0..7]
//   [44]     const_k = NORM_CONST - sum_i log(L_ii)
// ---------------------------------------------------------------------------
__global__ void mdn_precompute(const float* __restrict__ mu,
                               const float* __restrict__ Lc,
                               float* __restrict__ coeff) {
    int k = threadIdx.x;
    if (k >= K_COMP) return;
    const float* Lk = Lc + k * NC;

    float Lf[D_DIM][D_DIM];
    float r[D_DIM];
    float logdet = 0.0f;
    int idx = 0;
#pragma unroll
    for (int i = 0; i < D_DIM; i++) {
#pragma unroll
        for (int j = 0; j <= i; j++) {
            float v = Lk[idx++];
            if (j == i) {
                r[i] = 1.0f / v;
                logdet += logf(v);
            } else {
                Lf[i][j] = v;
            }
        }
    }

    float* out = coeff + k * CPK;
    int s = 0;
#pragma unroll
    for (int i = 1; i < D_DIM; i++) {
#pragma unroll
        for (int j = 0; j < i; j++) {
            out[s++] = r[i] * Lf[i][j];
        }
    }
#pragma unroll
    for (int i = 0; i < D_DIM; i++) out[28 + i] = r[i];
#pragma unroll
    for (int i = 0; i < D_DIM; i++) out[36 + i] = mu[k * D_DIM + i];
    out[44] = NORM_CONST - logdet;
}

// ---------------------------------------------------------------------------
// Main kernel: 4 threads per batch row, 16 components each.
//   Pass 1: cw[j] = const_k - 0.5*M  (register array), running max m.
//           (w = cw + log(pi) <= cw since pi<=1, so m = max(cw) is a safe
//            LSE shift: no overflow, and s >= 1e-10 so log(s) is finite.)
//   Pass 2: s = sum (pi + 1e-10) * exp(cw - m).   [zero logf in the loop]
//   Merge partial (m,s) across the 4 lanes of a row via __shfl_xor,
//   then lse = m + log(s), block-reduce, one atomicAdd per block.
// ---------------------------------------------------------------------------
__global__ __launch_bounds__(256, 4) void mdn_main(const float* __restrict__ pi,
                                                   const float* __restrict__ coeff,
                                                   const float* __restrict__ target,
                                                   float* __restrict__ out) {
    const int gtid = blockIdx.x * 256 + threadIdx.x;
    const int b = gtid >> 2;        // batch row
    const int t = gtid & 3;         // which quarter of the components

    // target row (32B): groups of 4 lanes share an address (broadcast)
    const float4* tp = (const float4*)(target + (size_t)b * D_DIM);
    float4 t0 = tp[0];
    float4 t1 = tp[1];
    float tv[D_DIM] = {t0.x, t0.y, t0.z, t0.w, t1.x, t1.y, t1.z, t1.w};

    const float* cb = coeff + (size_t)(t * KPT) * CPK;

    float cw[KPT];
    float m = -INFINITY;

#pragma unroll
    for (int j = 0; j < KPT; j++) {
        const float* c = cb + j * CPK;

        float d[D_DIM];
#pragma unroll
        for (int i = 0; i < D_DIM; i++) d[i] = tv[i] - c[36 + i];

        // forward substitution: z_i = r_i*d_i - sum_{j<i} S_ij * z_j
        float z[D_DIM];
        z[0] = d[0] * c[28];
#pragma unroll
        for (int i = 1; i < D_DIM; i++) {
            float acc = d[i] * c[28 + i];
            const int sbase = i * (i - 1) / 2;
#pragma unroll
            for (int jj = 0; jj < i; jj++) {
                acc = fmaf(-c[sbase + jj], z[jj], acc);
            }
            z[i] = acc;
        }

        float M = 0.0f;
#pragma unroll
        for (int i = 0; i < D_DIM; i++) M = fmaf(z[i], z[i], M);

        cw[j] = fmaf(-0.5f, M, c[44]);
        m = fmaxf(m, cw[j]);
    }

    // pass 2: weighted exp-sum (pi loads: 4x float4 per lane)
    const float* pib = pi + (size_t)b * K_COMP + t * KPT;
    float s = 0.0f;
#pragma unroll
    for (int q = 0; q < KPT / 4; q++) {
        float4 p4 = *(const float4*)(pib + 4 * q);
        float pv[4] = {p4.x, p4.y, p4.z, p4.w};
#pragma unroll
        for (int u = 0; u < 4; u++) {
            s += (pv[u] + 1e-10f) * __expf(cw[4 * q + u] - m);
        }
    }

    // merge the 4 per-lane partials of this row (lanes differ only in bits 0-1)
#pragma unroll
    for (int off = 1; off <= 2; off <<= 1) {
        float mo = __shfl_xor(m, off);
        float so = __shfl_xor(s, off);
        float nm = fmaxf(m, mo);
        s = s * __expf(m - nm) + so * __expf(mo - nm);
        m = nm;
    }

    float lse = m + __logf(s);
    float val = (t == 0) ? lse : 0.0f;

    // wave reduction (64 lanes)
#pragma unroll
    for (int off = 32; off > 0; off >>= 1) val += __shfl_down(val, off);

    __shared__ float wsum[4];
    const int lane = threadIdx.x & 63;
    const int wid = threadIdx.x >> 6;
    if (lane == 0) wsum[wid] = val;
    __syncthreads();
    if (threadIdx.x == 0) {
        float bs = wsum[0] + wsum[1] + wsum[2] + wsum[3];
        atomicAdd(out, bs * (-1.0f / (float)B_TOTAL));
    }
}

extern "C" void kernel_launch(void* const* d_in, const int* in_sizes, int n_in,
                              void* d_out, int out_size, void* d_ws, size_t ws_size,
                              hipStream_t stream) {
    const float* pi  = (const float*)d_in[0];
    const float* mu  = (const float*)d_in[1];
    const float* Lc  = (const float*)d_in[2];
    const float* tgt = (const float*)d_in[3];
    float* out   = (float*)d_out;
    float* coeff = (float*)d_ws;   // 64 * 48 * 4 = 12,288 bytes

    hipMemsetAsync(d_out, 0, sizeof(float), stream);
    mdn_precompute<<<1, 64, 0, stream>>>(mu, Lc, coeff);
    mdn_main<<<(B_TOTAL * 4) / 256, 256, 0, stream>>>(pi, coeff, tgt, out);
}

// Round 3
// 110.405 us; speedup vs baseline: 2.1571x; 2.1571x over previous
//
#include <hip/hip_runtime.h>
#include <math.h>

// Problem constants (fixed by setup_inputs)
#define B_TOTAL 131072
#define K_COMP  64
#define D_DIM   8
#define NC      36
#define CPK     48   // coeff floats per component: 28 S + 8 r + 8 mu + 1 const + 3 pad
#define KPW     16   // components per wave (4 waves split K=64)
#define ROWS_PB 64   // rows per block (one per lane)

// norm_const = -0.5 * D * log(2*pi)
#define NORM_CONST (-7.3515082656373815f)

// ---------------------------------------------------------------------------
// Precompute per-component coefficients into d_ws (also zeroes d_out):
//   [0..27]  S_ij = L_ij / L_ii   (i=1..7, j<i, index i*(i-1)/2+j)
//   [28..35] r_i  = 1 / L_ii
//   [36..43] mu_k[0..7]
//   [44]     const_k = NORM_CONST - sum_i log(L_ii)
// ---------------------------------------------------------------------------
__global__ void mdn_precompute(const float* __restrict__ mu,
                               const float* __restrict__ Lc,
                               float* __restrict__ coeff,
                               float* __restrict__ out) {
    int k = threadIdx.x;
    if (k == 0) out[0] = 0.0f;   // main kernel atomically accumulates into this
    if (k >= K_COMP) return;
    const float* Lk = Lc + k * NC;

    float Lf[D_DIM][D_DIM];
    float r[D_DIM];
    float logdet = 0.0f;
    int idx = 0;
#pragma unroll
    for (int i = 0; i < D_DIM; i++) {
#pragma unroll
        for (int j = 0; j <= i; j++) {
            float v = Lk[idx++];
            if (j == i) {
                r[i] = 1.0f / v;
                logdet += logf(v);
            } else {
                Lf[i][j] = v;
            }
        }
    }

    float* o = coeff + k * CPK;
    int s = 0;
#pragma unroll
    for (int i = 1; i < D_DIM; i++) {
#pragma unroll
        for (int j = 0; j < i; j++) {
            o[s++] = r[i] * Lf[i][j];
        }
    }
#pragma unroll
    for (int i = 0; i < D_DIM; i++) o[28 + i] = r[i];
#pragma unroll
    for (int i = 0; i < D_DIM; i++) o[36 + i] = mu[k * D_DIM + i];
    o[44] = NORM_CONST - logdet;
}

// ---------------------------------------------------------------------------
// Main kernel: block = 4 waves, 64 rows (lane = row).
// Wave w handles components [16w, 16w+16) -> coeff base is wave-uniform
// (forced scalar via readfirstlane) -> all coefficient reads are s_load,
// inner loop is pure VALU with SGPR operands.
//   Pass 1: cw[j] = const_k - 0.5*M, running max m (per lane).
//   Pass 2: s = sum (pi + 1e-10) * exp(cw - m).   [no logf in loops]
//   Cross-wave merge of (m,s) via LDS; wave 0 computes lse per row,
//   shuffle-reduces the 64 rows, one atomicAdd per block.
// ---------------------------------------------------------------------------
__global__ __launch_bounds__(256, 8) void mdn_main(const float* __restrict__ pi,
                                                   const float* __restrict__ coeff,
                                                   const float* __restrict__ target,
                                                   float* __restrict__ out) {
    const int lane = threadIdx.x & 63;
    const int w = __builtin_amdgcn_readfirstlane(threadIdx.x >> 6);
    const int b = blockIdx.x * ROWS_PB + lane;

    // target row (32B) — lanes read consecutive rows, coalesced
    const float4* tp = (const float4*)(target + (size_t)b * D_DIM);
    float4 t0 = tp[0];
    float4 t1 = tp[1];
    float tv[D_DIM] = {t0.x, t0.y, t0.z, t0.w, t1.x, t1.y, t1.z, t1.w};

    const float* cb = coeff + (size_t)(w * KPW) * CPK;   // SGPR base

    float cw[KPW];
    float m = -INFINITY;

#pragma unroll
    for (int j = 0; j < KPW; j++) {
        const float* c = cb + j * CPK;

        float d[D_DIM];
#pragma unroll
        for (int i = 0; i < D_DIM; i++) d[i] = tv[i] - c[36 + i];

        // forward substitution: z_i = r_i*d_i - sum_{jj<i} S_ijj * z_jj
        float z[D_DIM];
        z[0] = d[0] * c[28];
#pragma unroll
        for (int i = 1; i < D_DIM; i++) {
            float acc = d[i] * c[28 + i];
            const int sbase = i * (i - 1) / 2;
#pragma unroll
            for (int jj = 0; jj < i; jj++) {
                acc = fmaf(-c[sbase + jj], z[jj], acc);
            }
            z[i] = acc;
        }

        float M = 0.0f;
#pragma unroll
        for (int i = 0; i < D_DIM; i++) M = fmaf(z[i], z[i], M);

        cw[j] = fmaf(-0.5f, M, c[44]);
        m = fmaxf(m, cw[j]);
    }

    // pass 2: weighted exp-sum; pi[b][16w + 4q], 16B-aligned float4 per lane
    const float* pib = pi + (size_t)b * K_COMP + w * KPW;
    float s = 0.0f;
#pragma unroll
    for (int q = 0; q < KPW / 4; q++) {
        float4 p4 = *(const float4*)(pib + 4 * q);
        float pv[4] = {p4.x, p4.y, p4.z, p4.w};
#pragma unroll
        for (int u = 0; u < 4; u++) {
            s += (pv[u] + 1e-10f) * __expf(cw[4 * q + u] - m);
        }
    }

    // cross-wave merge via LDS: partials indexed [wave][row-lane]
    __shared__ float mpart[4][ROWS_PB];
    __shared__ float spart[4][ROWS_PB];
    mpart[w][lane] = m;
    spart[w][lane] = s;
    __syncthreads();

    if (threadIdx.x < 64) {
        float m0 = mpart[0][lane], s0 = spart[0][lane];
        float m1 = mpart[1][lane], s1 = spart[1][lane];
        float m2 = mpart[2][lane], s2 = spart[2][lane];
        float m3 = mpart[3][lane], s3 = spart[3][lane];
        float nm = fmaxf(fmaxf(m0, m1), fmaxf(m2, m3));
        float st = s0 * __expf(m0 - nm) + s1 * __expf(m1 - nm)
                 + s2 * __expf(m2 - nm) + s3 * __expf(m3 - nm);
        float lse = nm + __logf(st);

        // sum the 64 rows of this block
#pragma unroll
        for (int off = 32; off > 0; off >>= 1) lse += __shfl_down(lse, off);

        if (lane == 0) {
            atomicAdd(out, lse * (-1.0f / (float)B_TOTAL));
        }
    }
}

extern "C" void kernel_launch(void* const* d_in, const int* in_sizes, int n_in,
                              void* d_out, int out_size, void* d_ws, size_t ws_size,
                              hipStream_t stream) {
    const float* pi  = (const float*)d_in[0];
    const float* mu  = (const float*)d_in[1];
    const float* Lc  = (const float*)d_in[2];
    const float* tgt = (const float*)d_in[3];
    float* out   = (float*)d_out;
    float* coeff = (float*)d_ws;   // 64 * 48 * 4 = 12,288 bytes

    mdn_precompute<<<1, 64, 0, stream>>>(mu, Lc, coeff, out);
    mdn_main<<<B_TOTAL / ROWS_PB, 256, 0, stream>>>(pi, coeff, tgt, out);
}

// Round 4
// 100.130 us; speedup vs baseline: 2.3784x; 1.1026x over previous
//
#include <hip/hip_runtime.h>
#include <math.h>

// Problem constants (fixed by setup_inputs)
#define B_TOTAL 131072
#define K_COMP  64
#define D_DIM   8
#define NC      36
#define NFEAT   96     // K-dim: 64 quad (t_a*t_b all pairs) + 8 linear + 1 const + 23 pad
#define ROWS_PB 128    // rows per block (4 waves x 2 rowtiles x 16)
#define RT_PW   2      // 16-row tiles per wave

// norm_const = -0.5 * D * log(2*pi)
#define NORM_CONST (-7.3515082656373815f)

typedef __attribute__((ext_vector_type(8))) short bf16x8;
typedef __attribute__((ext_vector_type(4))) float f32x4;

static __device__ __forceinline__ unsigned short bf16_rne(float x) {
    unsigned u = __float_as_uint(x);
    u += 0x7FFF + ((u >> 16) & 1);
    return (unsigned short)(u >> 16);
}
static __device__ __forceinline__ float bf16_f32(unsigned short h) {
    return __uint_as_float(((unsigned)h) << 16);
}

// ---------------------------------------------------------------------------
// Precompute (1 block, 64 threads; one component per thread):
//   W = L^-1 (forward substitution), P = W^T W, h = P mu,
//   g = NORM_CONST - sum log L_ii - 0.5 mu^T P mu.
//   psi[e]: e=8a+b (a,b<8): -0.5*P[a][b]; e=64+b: h[b]; e=72: g; else 0.
//   Stored as split bf16: psi_hi = bf16(v), psi_lo = bf16(v - f32(psi_hi)).
// ---------------------------------------------------------------------------
__global__ void mdn_precompute(const float* __restrict__ mu,
                               const float* __restrict__ Lc,
                               unsigned short* __restrict__ psi_hi,
                               unsigned short* __restrict__ psi_lo,
                               float* __restrict__ out) {
    int k = threadIdx.x;
    if (k == 0) out[0] = 0.0f;   // main kernel atomically accumulates here
    if (k >= K_COMP) return;
    const float* Lk = Lc + k * NC;

    float L[D_DIM][D_DIM];
    float W[D_DIM][D_DIM];
#pragma unroll
    for (int i = 0; i < D_DIM; i++)
#pragma unroll
        for (int j = 0; j < D_DIM; j++) { L[i][j] = 0.0f; W[i][j] = 0.0f; }

    float logdet = 0.0f;
    int idx = 0;
#pragma unroll
    for (int i = 0; i < D_DIM; i++)
#pragma unroll
        for (int j = 0; j <= i; j++) {
            float v = Lk[idx++];
            L[i][j] = v;
            if (j == i) logdet += logf(v);
        }

    // W = L^-1 (lower triangular)
#pragma unroll
    for (int j = 0; j < D_DIM; j++) {
        W[j][j] = 1.0f / L[j][j];
#pragma unroll
        for (int i = 0; i < D_DIM; i++) {
            if (i > j) {
                float acc = 0.0f;
#pragma unroll
                for (int m = 0; m < D_DIM; m++)
                    if (m >= j && m < i) acc += L[i][m] * W[m][j];
                W[i][j] = -acc / L[i][i];
            }
        }
    }

    // P = W^T W
    float P[D_DIM][D_DIM];
#pragma unroll
    for (int a = 0; a < D_DIM; a++)
#pragma unroll
        for (int b = 0; b < D_DIM; b++) {
            float acc = 0.0f;
#pragma unroll
            for (int m = 0; m < D_DIM; m++) acc += W[m][a] * W[m][b];
            P[a][b] = acc;
        }

    float h[D_DIM];
    float qf = 0.0f;
#pragma unroll
    for (int i = 0; i < D_DIM; i++) {
        float acc = 0.0f;
#pragma unroll
        for (int j = 0; j < D_DIM; j++) acc += P[i][j] * mu[k * D_DIM + j];
        h[i] = acc;
        qf += mu[k * D_DIM + i] * acc;
    }
    float g = NORM_CONST - logdet - 0.5f * qf;

    float psi[NFEAT];
#pragma unroll
    for (int e = 0; e < NFEAT; e++) psi[e] = 0.0f;
#pragma unroll
    for (int a = 0; a < D_DIM; a++)
#pragma unroll
        for (int b = 0; b < D_DIM; b++) psi[8 * a + b] = -0.5f * P[a][b];
#pragma unroll
    for (int b = 0; b < D_DIM; b++) psi[64 + b] = h[b];
    psi[72] = g;

    unsigned short* oh = psi_hi + k * NFEAT;
    unsigned short* ol = psi_lo + k * NFEAT;
#pragma unroll
    for (int e = 0; e < NFEAT; e++) {
        unsigned short hi = bf16_rne(psi[e]);
        oh[e] = hi;
        ol[e] = bf16_rne(psi[e] - bf16_f32(hi));
    }
}

// ---------------------------------------------------------------------------
// Main kernel: block = 4 waves x 128 rows. Each wave: 2 tiles of 16 rows,
// all 64 components via 4 MFMA N-tiles (16x16x32 bf16, K=96 in 3 ksteps).
// Split-bf16 fp32 emulation: acc = Ahi*Bhi + Alo*Bhi + Ahi*Blo.
// A-layout: lane(m=lane&15, q=lane>>4) holds features e=32ks+8q+j:
//   a=4ks+q, b=j -> phi = t_a * t_j (regular, branch-free).
// kstep2: q==0 -> t_j (linear), q==1,j==0 -> 1 (const), else 0.
// C/D: col(comp)=lane&15+16nt, row=4q+reg. LSE per row via 16-lane butterfly.
// ---------------------------------------------------------------------------
__global__ __launch_bounds__(256, 4) void mdn_main(
        const float* __restrict__ pi,
        const unsigned short* __restrict__ psi_hi,
        const unsigned short* __restrict__ psi_lo,
        const float* __restrict__ target,
        float* __restrict__ out) {
    const int tid = threadIdx.x;
    const int lane = tid & 63;
    const int w = tid >> 6;
    const int q = lane >> 4;
    const int n = lane & 15;
    const int rowbase = blockIdx.x * ROWS_PB;

    __shared__ float Tl[ROWS_PB * D_DIM];   // 4 KB
    {
        const float4* src = (const float4*)(target + (size_t)rowbase * D_DIM);
        ((float4*)Tl)[tid] = src[tid];      // 256 x 16B = 1024 floats
    }
    __syncthreads();

    float lacc = 0.0f;

#pragma unroll
    for (int r = 0; r < RT_PW; r++) {
        const int row0 = (w * RT_PW + r) * 16;   // local row of tile origin

        // my A-row t-values
        const float4* trow = (const float4*)(Tl + (row0 + n) * D_DIM);
        float4 tlo = trow[0], thi = trow[1];
        float tv[D_DIM] = {tlo.x, tlo.y, tlo.z, tlo.w, thi.x, thi.y, thi.z, thi.w};

        // prefetch pi for this tile: row = 4q+reg, col = 16nt+n
        float pv[4][4];
#pragma unroll
        for (int reg = 0; reg < 4; reg++) {
            const float* pr = pi + (size_t)(rowbase + row0 + 4 * q + reg) * K_COMP + n;
#pragma unroll
            for (int nt = 0; nt < 4; nt++) pv[reg][nt] = pr[16 * nt];
        }

        // t_a selects: a = 4*ks + q
        float ta0 = (q & 2) ? ((q & 1) ? tlo.w : tlo.z) : ((q & 1) ? tlo.y : tlo.x);
        float ta1 = (q & 2) ? ((q & 1) ? thi.w : thi.z) : ((q & 1) ? thi.y : thi.x);

        bf16x8 Ahi[3], Alo[3];
#pragma unroll
        for (int j = 0; j < D_DIM; j++) {
            float f0 = ta0 * tv[j];
            unsigned short h0 = bf16_rne(f0);
            Ahi[0][j] = (short)h0;
            Alo[0][j] = (short)bf16_rne(f0 - bf16_f32(h0));

            float f1 = ta1 * tv[j];
            unsigned short h1 = bf16_rne(f1);
            Ahi[1][j] = (short)h1;
            Alo[1][j] = (short)bf16_rne(f1 - bf16_f32(h1));

            float f2 = (q == 0) ? tv[j] : ((q == 1 && j == 0) ? 1.0f : 0.0f);
            unsigned short h2 = bf16_rne(f2);
            Ahi[2][j] = (short)h2;
            Alo[2][j] = (short)bf16_rne(f2 - bf16_f32(h2));
        }

        f32x4 acc[4];
#pragma unroll
        for (int nt = 0; nt < 4; nt++) {
            const unsigned short* bh = psi_hi + ((16 * nt + n) * NFEAT + 8 * q);
            const unsigned short* bl = psi_lo + ((16 * nt + n) * NFEAT + 8 * q);
            f32x4 a = {0.0f, 0.0f, 0.0f, 0.0f};
#pragma unroll
            for (int ks = 0; ks < 3; ks++) {
                bf16x8 Bh = *(const bf16x8*)(bh + 32 * ks);
                bf16x8 Bl = *(const bf16x8*)(bl + 32 * ks);
                a = __builtin_amdgcn_mfma_f32_16x16x32_bf16(Ahi[ks], Bh, a, 0, 0, 0);
                a = __builtin_amdgcn_mfma_f32_16x16x32_bf16(Alo[ks], Bh, a, 0, 0, 0);
                a = __builtin_amdgcn_mfma_f32_16x16x32_bf16(Ahi[ks], Bl, a, 0, 0, 0);
            }
            acc[nt] = a;
        }

        // per-row LSE: row = 4q+reg held across the 16 lanes of this q-group
#pragma unroll
        for (int reg = 0; reg < 4; reg++) {
            float c0 = acc[0][reg], c1 = acc[1][reg], c2 = acc[2][reg], c3 = acc[3][reg];
            float mrow = fmaxf(fmaxf(c0, c1), fmaxf(c2, c3));
#pragma unroll
            for (int off = 1; off < 16; off <<= 1)
                mrow = fmaxf(mrow, __shfl_xor(mrow, off));
            float s = (pv[reg][0] + 1e-10f) * __expf(c0 - mrow)
                    + (pv[reg][1] + 1e-10f) * __expf(c1 - mrow)
                    + (pv[reg][2] + 1e-10f) * __expf(c2 - mrow)
                    + (pv[reg][3] + 1e-10f) * __expf(c3 - mrow);
#pragma unroll
            for (int off = 1; off < 16; off <<= 1)
                s += __shfl_xor(s, off);
            float lse = mrow + __logf(s);
            lacc += (n == 0) ? lse : 0.0f;   // count each row once
        }
    }

    // block reduction -> one atomic
#pragma unroll
    for (int off = 32; off > 0; off >>= 1) lacc += __shfl_down(lacc, off);
    __shared__ float wsum[4];
    if (lane == 0) wsum[w] = lacc;
    __syncthreads();
    if (tid == 0) {
        atomicAdd(out, (wsum[0] + wsum[1] + wsum[2] + wsum[3]) * (-1.0f / (float)B_TOTAL));
    }
}

extern "C" void kernel_launch(void* const* d_in, const int* in_sizes, int n_in,
                              void* d_out, int out_size, void* d_ws, size_t ws_size,
                              hipStream_t stream) {
    const float* pi  = (const float*)d_in[0];
    const float* mu  = (const float*)d_in[1];
    const float* Lc  = (const float*)d_in[2];
    const float* tgt = (const float*)d_in[3];
    float* out = (float*)d_out;

    unsigned short* psi_hi = (unsigned short*)d_ws;                       // 64*96*2 B
    unsigned short* psi_lo = (unsigned short*)((char*)d_ws + K_COMP * NFEAT * 2);

    mdn_precompute<<<1, 64, 0, stream>>>(mu, Lc, psi_hi, psi_lo, out);
    mdn_main<<<B_TOTAL / ROWS_PB, 256, 0, stream>>>(pi, psi_hi, psi_lo, tgt, out);
}